// Round 2
// baseline (483.108 us; speedup 1.0000x reference)
//
#include <hip/hip_runtime.h>

typedef __attribute__((ext_vector_type(8))) short short8;
typedef __attribute__((ext_vector_type(4))) float f32x4;

// fp32 -> bf16 bits, round-to-nearest-even
__device__ __forceinline__ short f2bf(float f) {
    unsigned u = __builtin_bit_cast(unsigned, f);
    u += 0x7fffu + ((u >> 16) & 1u);
    return (short)(u >> 16);
}

// Kernel 1: W_eff = sum_r s_r * W_r, stored TRANSPOSED as bf16: WT[n*128+k].
__global__ void weff_kernel(const float* __restrict__ W,
                            const float* __restrict__ S,
                            short* __restrict__ WT) {
    int idx = blockIdx.x * 256 + threadIdx.x;   // 0..16383 == k*128 + n
    int k = idx >> 7;
    int n = idx & 127;
    float acc = 0.f;
#pragma unroll
    for (int r = 0; r < 8; ++r) acc += S[r] * W[r * 16384 + idx];
    WT[n * 128 + k] = f2bf(acc);
}

// Kernel 2: C[M,128] = A[M,128] @ W_eff[128,128], bf16 MFMA, fp32 accumulate.
// Persistent grid-stride over 64-row chunks; 4 waves/block, 16 rows/wave.
// Swapped-operand MFMA (b,a) -> lane holds C[row=r16][cols t*16+quad*4+0..3]
// -> float4 C stores. Explicit register double-buffer on A loads.
#define BSTRIDE 136   // 128 + 8 bf16 pad: 16B-aligned, 2-way (free) LDS banking

__global__ __launch_bounds__(256, 3) void gemm_kernel(const float* __restrict__ A,
                                                      const short* __restrict__ WT,
                                                      float* __restrict__ C,
                                                      int N, int nchunks) {
    __shared__ __align__(16) short Bs[128 * BSTRIDE];

    int tid = threadIdx.x;
    // Stage W_eff^T (bf16) into padded LDS ONCE per persistent block.
#pragma unroll
    for (int it = 0; it < 8; ++it) {
        int chunk = it * 256 + tid;            // 0..2047
        int n  = chunk >> 4;                   // row of WT (output col)
        int kc = chunk & 15;                   // which 8-element k chunk
        *(short8*)&Bs[n * BSTRIDE + kc * 8] = ((const short8*)WT)[chunk];
    }
    __syncthreads();

    int wave = tid >> 6;
    int lane = tid & 63;
    int quad = lane >> 4;
    int r16  = lane & 15;

    const short* bbase = &Bs[r16 * BSTRIDE];   // + t*16*BSTRIDE + kk*32 + quad*8
    int stride = gridDim.x;

    f32x4 cur[8], nxt[8];

    int c0 = blockIdx.x;
    // Prologue: issue loads for first chunk.
    {
        int rowA = c0 * 64 + wave * 16 + r16;
        if (rowA >= N) rowA = N - 1;           // clamp: junk rows never stored
        const float* arow = A + (long)rowA * 128;
#pragma unroll
        for (int kk = 0; kk < 4; ++kk) {
            cur[kk * 2]     = *(const f32x4*)(arow + kk * 32 + quad * 8);
            cur[kk * 2 + 1] = *(const f32x4*)(arow + kk * 32 + quad * 8 + 4);
        }
    }

    for (int c = c0; c < nchunks; c += stride) {
        // Prefetch next chunk's A into nxt (in flight during compute below).
        int cn = c + stride;
        if (cn < nchunks) {
            int rowA = cn * 64 + wave * 16 + r16;
            if (rowA >= N) rowA = N - 1;
            const float* arow = A + (long)rowA * 128;
#pragma unroll
            for (int kk = 0; kk < 4; ++kk) {
                nxt[kk * 2]     = *(const f32x4*)(arow + kk * 32 + quad * 8);
                nxt[kk * 2 + 1] = *(const f32x4*)(arow + kk * 32 + quad * 8 + 4);
            }
        }

        f32x4 acc[8];
#pragma unroll
        for (int t = 0; t < 8; ++t) acc[t] = (f32x4)(0.f);

#pragma unroll
        for (int kk = 0; kk < 4; ++kk) {
            f32x4 p = cur[kk * 2];
            f32x4 q = cur[kk * 2 + 1];
            short8 afrag;
            afrag[0] = f2bf(p[0]); afrag[1] = f2bf(p[1]);
            afrag[2] = f2bf(p[2]); afrag[3] = f2bf(p[3]);
            afrag[4] = f2bf(q[0]); afrag[5] = f2bf(q[1]);
            afrag[6] = f2bf(q[2]); afrag[7] = f2bf(q[3]);
            const short* bk = bbase + kk * 32 + quad * 8;
#pragma unroll
            for (int t = 0; t < 8; ++t) {
                // B frag: WT[(t*16+r16)][kk*32 + quad*8 .. +7]
                short8 bfrag = *(const short8*)(bk + t * 16 * BSTRIDE);
                // Swapped operands: D[n][m] = C[m][n] -> lane holds
                // C[row = r16][col = t*16 + quad*4 + reg]  (float4-storable)
                acc[t] = __builtin_amdgcn_mfma_f32_16x16x32_bf16(bfrag, afrag, acc[t], 0, 0, 0);
            }
        }

        int row = c * 64 + wave * 16 + r16;
        if (row < N) {
            float* crow = C + (long)row * 128 + quad * 4;
#pragma unroll
            for (int t = 0; t < 8; ++t) {
                __builtin_nontemporal_store(acc[t], (f32x4*)(crow + t * 16));
            }
        }

#pragma unroll
        for (int i = 0; i < 8; ++i) cur[i] = nxt[i];
    }
}

extern "C" void kernel_launch(void* const* d_in, const int* in_sizes, int n_in,
                              void* d_out, int out_size, void* d_ws, size_t ws_size,
                              hipStream_t stream) {
    const float* inputs = (const float*)d_in[0];     // [N,128] fp32
    const float* W      = (const float*)d_in[1];     // [8,128,128] fp32
    const float* S      = (const float*)d_in[2];     // [8,1] fp32
    float* out = (float*)d_out;                      // [N,128] fp32
    short* WT  = (short*)d_ws;                       // [128,128] bf16 (W_eff^T)

    int N = in_sizes[0] / 128;

    weff_kernel<<<64, 256, 0, stream>>>(W, S, WT);

    int nchunks = (N + 63) / 64;
    int grid = nchunks < 1024 ? nchunks : 1024;
    gemm_kernel<<<grid, 256, 0, stream>>>(inputs, WT, out, N, nchunks);
}